// Round 1
// baseline (642.531 us; speedup 1.0000x reference)
//
#include <hip/hip_runtime.h>
#include <math.h>

#define BSZ 128
#define KTOT 196608            // 3*256*256
#define NBLK1 512
#define KC (KTOT / NBLK1)      // 384
#define KTILE 32
#define NTILE (KC / KTILE)     // 12
#define LSTR 132               // padded k-major stride (16B-aligned, breaks pow2 conflicts)
#define REGF 0.01f
#define NITER 100

__global__ void zero_kernel(float* p, int n) {
    int i = blockIdx.x * blockDim.x + threadIdx.x;
    if (i < n) p[i] = 0.f;
}

// Split-K GEMM: S[i][j] += dot(delta_i, tgt_j) over this block's K-chunk,
// plus squared-norm partials for rows of delta (x2) and tgt (y2).
__global__ __launch_bounds__(256, 2) void dot_kernel(
    const float* __restrict__ imgs, const float* __restrict__ imgs_w,
    const float* __restrict__ target, float* __restrict__ S,
    float* __restrict__ x2, float* __restrict__ y2)
{
    __shared__ float As[KTILE * LSTR];   // [kk][row], delta tile
    __shared__ float Bs[KTILE * LSTR];   // [kk][col], target tile
    __shared__ float x2s[BSZ];
    __shared__ float y2s[BSZ];
    const int t = threadIdx.x;
    const long kbase = (long)blockIdx.x * KC;
    if (t < BSZ) { x2s[t] = 0.f; y2s[t] = 0.f; }

    // compute mapping: 4 waves in 2x2 quadrants of 64x64; lane -> 8x8 sub-tile
    const int lane = t & 63;
    const int wave = t >> 6;
    const int row0 = (wave >> 1) * 64 + (lane >> 3) * 8;
    const int col0 = (wave & 1) * 64 + (lane & 7) * 8;

    float acc[8][8];
#pragma unroll
    for (int i = 0; i < 8; ++i)
#pragma unroll
        for (int j = 0; j < 8; ++j) acc[i][j] = 0.f;
    float x2p[4] = {0.f, 0.f, 0.f, 0.f};
    float y2p[4] = {0.f, 0.f, 0.f, 0.f};

    for (int tile = 0; tile < NTILE; ++tile) {
        const long kb = kbase + (long)tile * KTILE;
        __syncthreads();   // protect LDS from previous tile's readers
#pragma unroll
        for (int q = 0; q < 4; ++q) {
            const int linear = q * 256 + t;      // [0,1024)
            const int row = linear >> 3;         // [0,128)
            const int f4  = linear & 7;          // which float4 in the 32-wide k-slab
            const long g = (long)row * KTOT + kb + f4 * 4;
            const float4 aw = *(const float4*)(imgs_w + g);
            const float4 ai = *(const float4*)(imgs + g);
            const float4 bt = *(const float4*)(target + g);
            const float ax = aw.x - ai.x, ay = aw.y - ai.y;
            const float az = aw.z - ai.z, aww = aw.w - ai.w;
            const int kk = f4 * 4;
            As[(kk + 0) * LSTR + row] = ax;
            As[(kk + 1) * LSTR + row] = ay;
            As[(kk + 2) * LSTR + row] = az;
            As[(kk + 3) * LSTR + row] = aww;
            Bs[(kk + 0) * LSTR + row] = bt.x;
            Bs[(kk + 1) * LSTR + row] = bt.y;
            Bs[(kk + 2) * LSTR + row] = bt.z;
            Bs[(kk + 3) * LSTR + row] = bt.w;
            x2p[q] += ax * ax + ay * ay + az * az + aww * aww;
            y2p[q] += bt.x * bt.x + bt.y * bt.y + bt.z * bt.z + bt.w * bt.w;
        }
        __syncthreads();
#pragma unroll 2
        for (int kk = 0; kk < KTILE; ++kk) {
            const float4 a01 = *(const float4*)&As[kk * LSTR + row0];
            const float4 a23 = *(const float4*)&As[kk * LSTR + row0 + 4];
            const float4 b01 = *(const float4*)&Bs[kk * LSTR + col0];
            const float4 b23 = *(const float4*)&Bs[kk * LSTR + col0 + 4];
            const float av[8] = {a01.x, a01.y, a01.z, a01.w, a23.x, a23.y, a23.z, a23.w};
            const float bv[8] = {b01.x, b01.y, b01.z, b01.w, b23.x, b23.y, b23.z, b23.w};
#pragma unroll
            for (int i = 0; i < 8; ++i)
#pragma unroll
                for (int j = 0; j < 8; ++j)
                    acc[i][j] = fmaf(av[i], bv[j], acc[i][j]);
        }
    }

    // norm partials: LDS combine, then one global atomic per row/col per block
#pragma unroll
    for (int q = 0; q < 4; ++q) {
        const int row = (q * 256 + t) >> 3;
        atomicAdd(&x2s[row], x2p[q]);
        atomicAdd(&y2s[row], y2p[q]);
    }
    __syncthreads();
    if (t < BSZ) {
        atomicAdd(&x2[t], x2s[t]);
        atomicAdd(&y2[t], y2s[t]);
    }
#pragma unroll
    for (int i = 0; i < 8; ++i)
#pragma unroll
        for (int j = 0; j < 8; ++j)
            atomicAdd(&S[(row0 + i) * BSZ + col0 + j], acc[i][j]);
}

// Single-block sinkhorn. Uses exp-factorization: since
// lse_j(C_ij - u_i - v_j) = -u_i + m_i + log(sum_j exp(C_ij - m_i) * exp(-v_j)),
// the exp of C is iteration-invariant -> precompute into registers, each
// iteration is two 128x128 matvecs.
__global__ __launch_bounds__(1024) void sinkhorn_kernel(
    const float* __restrict__ S, const float* __restrict__ x2,
    const float* __restrict__ y2, float* __restrict__ out)
{
    __shared__ float C_lds[BSZ * BSZ];   // 64 KB, only for setup
    __shared__ float w_s[BSZ];           // exp(-v)
    __shared__ float g_s[BSZ];           // exp(-u)
    __shared__ float u_s[BSZ], v_s[BSZ];
    const int t = threadIdx.x;
    const int lane = t & 63;
    const int wave = t >> 6;
    const int rgrp = wave * 8 + (lane >> 3);  // row (row-pass) / col (col-pass) index
    const int off16 = (lane & 7) * 16;        // this lane's 16-element chunk

    // build C = sqrt(relu(x2_i + y2_j - 2*S_ij))
    for (int q = 0; q < 16; ++q) {
        const int idx = q * 1024 + t;
        const int i = idx >> 7, j = idx & 127;
        const float sq = x2[i] + y2[j] - 2.f * S[idx];
        C_lds[idx] = sqrtf(fmaxf(sq, 0.f));
    }
    if (t < BSZ) w_s[t] = 1.f;   // v=0 -> exp(-v)=1
    __syncthreads();

    // register fragments: rowE = exp(C[rgrp][off16+k] - rowmax),
    //                     colF = exp(C[off16+k][rgrp] - colmax)
    float rowE[16], colF[16], mrow, mcol;
    {
        float tmp[16]; float m = -1e30f;
#pragma unroll
        for (int k = 0; k < 16; ++k) { tmp[k] = C_lds[rgrp * BSZ + off16 + k]; m = fmaxf(m, tmp[k]); }
        m = fmaxf(m, __shfl_xor(m, 1)); m = fmaxf(m, __shfl_xor(m, 2)); m = fmaxf(m, __shfl_xor(m, 4));
        mrow = m;
#pragma unroll
        for (int k = 0; k < 16; ++k) rowE[k] = __expf(tmp[k] - mrow);
    }
    {
        float tmp[16]; float m = -1e30f;
#pragma unroll
        for (int k = 0; k < 16; ++k) { tmp[k] = C_lds[(off16 + k) * BSZ + rgrp]; m = fmaxf(m, tmp[k]); }
        m = fmaxf(m, __shfl_xor(m, 1)); m = fmaxf(m, __shfl_xor(m, 2)); m = fmaxf(m, __shfl_xor(m, 4));
        mcol = m;
#pragma unroll
        for (int k = 0; k < 16; ++k) colF[k] = __expf(tmp[k] - mcol);
    }

    const float log_ab = -logf(128.f);
    float u_cur = 0.f, v_cur = 0.f;

    for (int it = 0; it < NITER; ++it) {
        // u = REG*(log_a - lse_j(C_ij - v_j) + u_old)
        float acc = 0.f;
#pragma unroll
        for (int k = 0; k < 16; ++k) acc += rowE[k] * w_s[off16 + k];
        acc += __shfl_xor(acc, 1); acc += __shfl_xor(acc, 2); acc += __shfl_xor(acc, 4);
        const float lse = mrow + __logf(acc);
        u_cur = REGF * (log_ab - lse + u_cur);
        if ((lane & 7) == 0) g_s[rgrp] = __expf(-u_cur);
        __syncthreads();
        // v = REG*(log_b - lse_i(C_ij - u_new_i) + v_old)
        float acc2 = 0.f;
#pragma unroll
        for (int k = 0; k < 16; ++k) acc2 += colF[k] * g_s[off16 + k];
        acc2 += __shfl_xor(acc2, 1); acc2 += __shfl_xor(acc2, 2); acc2 += __shfl_xor(acc2, 4);
        const float lse2 = mcol + __logf(acc2);
        v_cur = REGF * (log_ab - lse2 + v_cur);
        if ((lane & 7) == 0) w_s[rgrp] = __expf(-v_cur);
        __syncthreads();
    }

    if ((lane & 7) == 0) { u_s[rgrp] = u_cur; v_s[rgrp] = v_cur; }
    __syncthreads();
    if (t == 0) {
        float su = 0.f;
        for (int i = 0; i < BSZ; ++i) su += u_s[i] + v_s[i];
        out[0] = su / 128.f;   // sum(u*a + v*b), a=b=1/128
    }
}

extern "C" void kernel_launch(void* const* d_in, const int* in_sizes, int n_in,
                              void* d_out, int out_size, void* d_ws, size_t ws_size,
                              hipStream_t stream) {
    const float* imgs   = (const float*)d_in[0];
    const float* imgs_w = (const float*)d_in[1];
    const float* target = (const float*)d_in[2];
    float* out = (float*)d_out;
    float* wsf = (float*)d_ws;
    float* S  = wsf;                 // 128*128 dot partial sums
    float* x2 = wsf + BSZ * BSZ;     // 128 row norms of delta
    float* y2 = x2 + BSZ;            // 128 row norms of target

    const int nzero = BSZ * BSZ + 2 * BSZ;
    zero_kernel<<<(nzero + 255) / 256, 256, 0, stream>>>(wsf, nzero);
    dot_kernel<<<NBLK1, 256, 0, stream>>>(imgs, imgs_w, target, S, x2, y2);
    sinkhorn_kernel<<<1, 1024, 0, stream>>>(S, x2, y2, out);
}

// Round 2
// 385.959 us; speedup vs baseline: 1.6648x; 1.6648x over previous
//
#include <hip/hip_runtime.h>
#include <math.h>

#define BSZ 128
#define KTOT 196608            // 3*256*256
#define NBLK1 512
#define KC (KTOT / NBLK1)      // 384
#define KTILE 32
#define NTILE (KC / KTILE)     // 12
#define LSTR 132               // padded k-major stride
#define REGF 0.01f
#define NITER 16               // map contracts at ~0.02/iter; fp32-converged by ~8

__global__ void zero_kernel(float* p, int n) {
    int i = blockIdx.x * blockDim.x + threadIdx.x;
    if (i < n) p[i] = 0.f;
}

template <bool ATOMIC>
__global__ __launch_bounds__(256) void dot_kernel(
    const float* __restrict__ imgs, const float* __restrict__ imgs_w,
    const float* __restrict__ target, float* __restrict__ P,
    float* __restrict__ x2, float* __restrict__ y2)
{
    __shared__ float As[KTILE * LSTR];
    __shared__ float Bs[KTILE * LSTR];
    __shared__ float x2s[BSZ];
    __shared__ float y2s[BSZ];
    const int t = threadIdx.x;
    const long kbase = (long)blockIdx.x * KC;
    if (t < BSZ) { x2s[t] = 0.f; y2s[t] = 0.f; }

    const int lane = t & 63;
    const int wave = t >> 6;
    const int row0 = (wave >> 1) * 64 + (lane >> 3) * 8;
    const int col0 = (wave & 1) * 64 + (lane & 7) * 8;

    int rowq[4], kkq[4];
    long gq[4];
#pragma unroll
    for (int q = 0; q < 4; ++q) {
        const int linear = q * 256 + t;
        rowq[q] = linear >> 3;
        const int f4 = linear & 7;
        kkq[q] = f4 * 4;
        gq[q] = (long)rowq[q] * KTOT + kbase + f4 * 4;
    }

    float acc[8][8];
#pragma unroll
    for (int i = 0; i < 8; ++i)
#pragma unroll
        for (int j = 0; j < 8; ++j) acc[i][j] = 0.f;
    float x2p[4] = {0.f, 0.f, 0.f, 0.f};
    float y2p[4] = {0.f, 0.f, 0.f, 0.f};

    float4 rw[4], ri[4], rt[4];
#pragma unroll
    for (int q = 0; q < 4; ++q) {
        rw[q] = *(const float4*)(imgs_w + gq[q]);
        ri[q] = *(const float4*)(imgs + gq[q]);
        rt[q] = *(const float4*)(target + gq[q]);
    }

    for (int tile = 0; tile < NTILE; ++tile) {
        __syncthreads();   // previous tile's readers done; LDS free
#pragma unroll
        for (int q = 0; q < 4; ++q) {
            const float ax = rw[q].x - ri[q].x, ay = rw[q].y - ri[q].y;
            const float az = rw[q].z - ri[q].z, aw = rw[q].w - ri[q].w;
            const int kk = kkq[q], row = rowq[q];
            As[(kk + 0) * LSTR + row] = ax;
            As[(kk + 1) * LSTR + row] = ay;
            As[(kk + 2) * LSTR + row] = az;
            As[(kk + 3) * LSTR + row] = aw;
            Bs[(kk + 0) * LSTR + row] = rt[q].x;
            Bs[(kk + 1) * LSTR + row] = rt[q].y;
            Bs[(kk + 2) * LSTR + row] = rt[q].z;
            Bs[(kk + 3) * LSTR + row] = rt[q].w;
            x2p[q] += ax * ax + ay * ay + az * az + aw * aw;
            y2p[q] += rt[q].x * rt[q].x + rt[q].y * rt[q].y
                    + rt[q].z * rt[q].z + rt[q].w * rt[q].w;
        }
        // prefetch next tile into registers — in flight during compute below
        if (tile + 1 < NTILE) {
            const long koff = (long)(tile + 1) * KTILE;
#pragma unroll
            for (int q = 0; q < 4; ++q) {
                const long g = gq[q] + koff;
                rw[q] = *(const float4*)(imgs_w + g);
                ri[q] = *(const float4*)(imgs + g);
                rt[q] = *(const float4*)(target + g);
            }
        }
        __syncthreads();
#pragma unroll 2
        for (int kk = 0; kk < KTILE; ++kk) {
            const float4 a01 = *(const float4*)&As[kk * LSTR + row0];
            const float4 a23 = *(const float4*)&As[kk * LSTR + row0 + 4];
            const float4 b01 = *(const float4*)&Bs[kk * LSTR + col0];
            const float4 b23 = *(const float4*)&Bs[kk * LSTR + col0 + 4];
            const float av[8] = {a01.x, a01.y, a01.z, a01.w, a23.x, a23.y, a23.z, a23.w};
            const float bv[8] = {b01.x, b01.y, b01.z, b01.w, b23.x, b23.y, b23.z, b23.w};
#pragma unroll
            for (int i = 0; i < 8; ++i)
#pragma unroll
                for (int j = 0; j < 8; ++j)
                    acc[i][j] = fmaf(av[i], bv[j], acc[i][j]);
        }
    }

#pragma unroll
    for (int q = 0; q < 4; ++q) {
        atomicAdd(&x2s[rowq[q]], x2p[q]);
        atomicAdd(&y2s[rowq[q]], y2p[q]);
    }
    __syncthreads();
    if (t < BSZ) {
        atomicAdd(&x2[t], x2s[t]);
        atomicAdd(&y2[t], y2s[t]);
    }

    if (ATOMIC) {
#pragma unroll
        for (int i = 0; i < 8; ++i)
#pragma unroll
            for (int j = 0; j < 8; ++j)
                atomicAdd(&P[(row0 + i) * BSZ + col0 + j], acc[i][j]);
    } else {
        float* Pb = P + ((size_t)blockIdx.x << 14);
#pragma unroll
        for (int i = 0; i < 8; ++i) {
            *(float4*)(Pb + (row0 + i) * BSZ + col0) =
                make_float4(acc[i][0], acc[i][1], acc[i][2], acc[i][3]);
            *(float4*)(Pb + (row0 + i) * BSZ + col0 + 4) =
                make_float4(acc[i][4], acc[i][5], acc[i][6], acc[i][7]);
        }
    }
}

__global__ __launch_bounds__(256) void reduce_kernel(
    const float* __restrict__ P, const float* __restrict__ x2,
    const float* __restrict__ y2, float* __restrict__ C)
{
    const int o = blockIdx.x * 256 + threadIdx.x;
    float a0 = 0.f, a1 = 0.f, a2 = 0.f, a3 = 0.f;
#pragma unroll 4
    for (int k = 0; k < NBLK1; k += 4) {
        a0 += P[((size_t)(k + 0) << 14) + o];
        a1 += P[((size_t)(k + 1) << 14) + o];
        a2 += P[((size_t)(k + 2) << 14) + o];
        a3 += P[((size_t)(k + 3) << 14) + o];
    }
    const float s = (a0 + a1) + (a2 + a3);
    const int i = o >> 7, j = o & 127;
    C[o] = sqrtf(fmaxf(x2[i] + y2[j] - 2.f * s, 0.f));
}

__global__ __launch_bounds__(256) void cbuild_kernel(
    const float* __restrict__ S, const float* __restrict__ x2,
    const float* __restrict__ y2, float* __restrict__ C)
{
    const int o = blockIdx.x * 256 + threadIdx.x;
    const int i = o >> 7, j = o & 127;
    C[o] = sqrtf(fmaxf(x2[i] + y2[j] - 2.f * S[o], 0.f));
}

__global__ __launch_bounds__(1024) void sinkhorn_kernel(
    const float* __restrict__ Cg, float* __restrict__ out)
{
    __shared__ float C_lds[BSZ * BSZ];
    __shared__ float w_s[BSZ];
    __shared__ float g_s[BSZ];
    __shared__ float u_s[BSZ], v_s[BSZ];
    const int t = threadIdx.x;
    const int lane = t & 63;
    const int wave = t >> 6;
    const int rgrp = wave * 8 + (lane >> 3);
    const int off16 = (lane & 7) * 16;

#pragma unroll
    for (int q = 0; q < 4; ++q)
        *(float4*)&C_lds[q * 4096 + t * 4] = *(const float4*)&Cg[q * 4096 + t * 4];
    if (t < BSZ) w_s[t] = 1.f;
    __syncthreads();

    float rowE[16], colF[16], mrow, mcol;
    {
        float tmp[16]; float m = -1e30f;
#pragma unroll
        for (int k = 0; k < 16; ++k) { tmp[k] = C_lds[rgrp * BSZ + off16 + k]; m = fmaxf(m, tmp[k]); }
        m = fmaxf(m, __shfl_xor(m, 1)); m = fmaxf(m, __shfl_xor(m, 2)); m = fmaxf(m, __shfl_xor(m, 4));
        mrow = m;
#pragma unroll
        for (int k = 0; k < 16; ++k) rowE[k] = __expf(tmp[k] - mrow);
    }
    {
        float tmp[16]; float m = -1e30f;
#pragma unroll
        for (int k = 0; k < 16; ++k) { tmp[k] = C_lds[(off16 + k) * BSZ + rgrp]; m = fmaxf(m, tmp[k]); }
        m = fmaxf(m, __shfl_xor(m, 1)); m = fmaxf(m, __shfl_xor(m, 2)); m = fmaxf(m, __shfl_xor(m, 4));
        mcol = m;
#pragma unroll
        for (int k = 0; k < 16; ++k) colF[k] = __expf(tmp[k] - mcol);
    }

    const float log_ab = -logf(128.f);
    float u_cur = 0.f, v_cur = 0.f;

    for (int it = 0; it < NITER; ++it) {
        float acc = 0.f;
#pragma unroll
        for (int k = 0; k < 16; ++k) acc += rowE[k] * w_s[off16 + k];
        acc += __shfl_xor(acc, 1); acc += __shfl_xor(acc, 2); acc += __shfl_xor(acc, 4);
        const float lse = mrow + __logf(acc);
        u_cur = REGF * (log_ab - lse + u_cur);
        if ((lane & 7) == 0) g_s[rgrp] = __expf(-u_cur);
        __syncthreads();
        float acc2 = 0.f;
#pragma unroll
        for (int k = 0; k < 16; ++k) acc2 += colF[k] * g_s[off16 + k];
        acc2 += __shfl_xor(acc2, 1); acc2 += __shfl_xor(acc2, 2); acc2 += __shfl_xor(acc2, 4);
        const float lse2 = mcol + __logf(acc2);
        v_cur = REGF * (log_ab - lse2 + v_cur);
        if ((lane & 7) == 0) w_s[rgrp] = __expf(-v_cur);
        __syncthreads();
    }

    if ((lane & 7) == 0) { u_s[rgrp] = u_cur; v_s[rgrp] = v_cur; }
    __syncthreads();
    if (t == 0) {
        float su = 0.f;
        for (int i = 0; i < BSZ; ++i) su += u_s[i] + v_s[i];
        out[0] = su / 128.f;
    }
}

extern "C" void kernel_launch(void* const* d_in, const int* in_sizes, int n_in,
                              void* d_out, int out_size, void* d_ws, size_t ws_size,
                              hipStream_t stream) {
    const float* imgs   = (const float*)d_in[0];
    const float* imgs_w = (const float*)d_in[1];
    const float* target = (const float*)d_in[2];
    float* out = (float*)d_out;
    float* wsf = (float*)d_ws;

    const size_t needP = (size_t)NBLK1 * BSZ * BSZ;
    const size_t need_bytes = (needP + 2 * BSZ + BSZ * BSZ) * 4;
    if (ws_size >= need_bytes) {
        float* P  = wsf;
        float* x2 = wsf + needP;
        float* y2 = x2 + BSZ;
        float* C  = y2 + BSZ;
        zero_kernel<<<1, 256, 0, stream>>>(x2, 2 * BSZ);
        dot_kernel<false><<<NBLK1, 256, 0, stream>>>(imgs, imgs_w, target, P, x2, y2);
        reduce_kernel<<<BSZ * BSZ / 256, 256, 0, stream>>>(P, x2, y2, C);
        sinkhorn_kernel<<<1, 1024, 0, stream>>>(C, out);
    } else {
        float* S  = wsf;
        float* x2 = wsf + BSZ * BSZ;
        float* y2 = x2 + BSZ;
        float* C  = y2 + BSZ;
        const int nzero = BSZ * BSZ + 2 * BSZ;
        zero_kernel<<<(nzero + 255) / 256, 256, 0, stream>>>(wsf, nzero);
        dot_kernel<true><<<NBLK1, 256, 0, stream>>>(imgs, imgs_w, target, S, x2, y2);
        cbuild_kernel<<<BSZ * BSZ / 256, 256, 0, stream>>>(S, x2, y2, C);
        sinkhorn_kernel<<<1, 1024, 0, stream>>>(C, out);
    }
}

// Round 3
// 351.875 us; speedup vs baseline: 1.8260x; 1.0969x over previous
//
#include <hip/hip_runtime.h>
#include <math.h>

#define BSZ 128
#define KTOT 196608            // 3*256*256
#define NBLK1 256              // split-K blocks (1 per CU)
#define KC (KTOT / NBLK1)      // 768
#define BK 32                  // k per slab
#define NSLAB (KC / BK)        // 24
#define RS 40                  // LDS row stride in bf16 (32 + 8 pad; 80B rows)
#define REGF 0.01f
#define NITER 8                // contraction ~0.02/iter; converged ~1e-13 by iter 8

typedef short bf16x8 __attribute__((ext_vector_type(8)));
typedef float f32x4 __attribute__((ext_vector_type(4)));

__device__ __forceinline__ unsigned short f2bf(float f) {
    union { float f; unsigned int u; } x; x.f = f;
    unsigned int r = x.u + 0x7fffu + ((x.u >> 16) & 1u);   // RNE
    return (unsigned short)(r >> 16);
}

// Split-K bf16-MFMA GEMM: block b computes the full 128x128 partial dot over
// its 768-long K-chunk, converting fp32->bf16 on the fly (each input element
// read exactly once device-wide). Norms accumulated in fp32 (pre-rounding).
__global__ __launch_bounds__(256, 2) void dot_kernel(
    const float* __restrict__ imgs, const float* __restrict__ imgs_w,
    const float* __restrict__ target, float* __restrict__ P,
    float* __restrict__ x2P, float* __restrict__ y2P)
{
    __shared__ unsigned short Abf[BSZ * RS];   // delta, [row][k] k-contiguous
    __shared__ unsigned short Bbf[BSZ * RS];   // target
    __shared__ float x2s[BSZ], y2s[BSZ];
    const int t = threadIdx.x;
    const int bid = blockIdx.x;
    const long kbase = (long)bid * KC;
    if (t < BSZ) { x2s[t] = 0.f; y2s[t] = 0.f; }

    const int lane = t & 63;
    const int wv = t >> 6;
    const int fr = lane & 15;     // fragment row/col within 16-tile
    const int fq = lane >> 4;     // quad
    const int wrow0 = wv * 32;    // this wave's output-row block

    // staging coords: q in 0..3 -> row = 32q + t/8, f4 = t&7 (4 floats at f4*4)
    const int f4 = t & 7;
    const int rbase = t >> 3;

    f32x4 acc[2][8];
#pragma unroll
    for (int rt = 0; rt < 2; ++rt)
#pragma unroll
        for (int ct = 0; ct < 8; ++ct) acc[rt][ct] = (f32x4){0.f, 0.f, 0.f, 0.f};
    float x2p[4] = {0.f, 0.f, 0.f, 0.f};
    float y2p[4] = {0.f, 0.f, 0.f, 0.f};

    float4 rw[4], ri[4], rt4[4];
    long gq[4];
#pragma unroll
    for (int q = 0; q < 4; ++q) {
        gq[q] = (long)(32 * q + rbase) * KTOT + kbase + f4 * 4;
        rw[q]  = *(const float4*)(imgs_w + gq[q]);
        ri[q]  = *(const float4*)(imgs + gq[q]);
        rt4[q] = *(const float4*)(target + gq[q]);
    }

    for (int s = 0; s < NSLAB; ++s) {
        __syncthreads();   // prior slab's readers done
        // convert + stage this slab (from prefetched regs)
#pragma unroll
        for (int q = 0; q < 4; ++q) {
            const float d0 = rw[q].x - ri[q].x, d1 = rw[q].y - ri[q].y;
            const float d2 = rw[q].z - ri[q].z, d3 = rw[q].w - ri[q].w;
            const float b0 = rt4[q].x, b1 = rt4[q].y, b2 = rt4[q].z, b3 = rt4[q].w;
            x2p[q] += d0 * d0 + d1 * d1 + d2 * d2 + d3 * d3;
            y2p[q] += b0 * b0 + b1 * b1 + b2 * b2 + b3 * b3;
            const int idx = (32 * q + rbase) * RS + f4 * 4;
            ushort4 pa; pa.x = f2bf(d0); pa.y = f2bf(d1); pa.z = f2bf(d2); pa.w = f2bf(d3);
            ushort4 pb; pb.x = f2bf(b0); pb.y = f2bf(b1); pb.z = f2bf(b2); pb.w = f2bf(b3);
            *(ushort4*)&Abf[idx] = pa;
            *(ushort4*)&Bbf[idx] = pb;
        }
        // prefetch next slab into registers (in flight across the MFMA section)
        if (s + 1 < NSLAB) {
            const long ko = (long)(s + 1) * BK;
#pragma unroll
            for (int q = 0; q < 4; ++q) {
                rw[q]  = *(const float4*)(imgs_w + gq[q] + ko);
                ri[q]  = *(const float4*)(imgs + gq[q] + ko);
                rt4[q] = *(const float4*)(target + gq[q] + ko);
            }
        }
        __syncthreads();   // slab staged
        // one K=32 MFMA step: 2 a-frags (rows), 8 b-frags (cols), 16 MFMA
        const bf16x8 a0 = *(const bf16x8*)&Abf[(wrow0 + fr) * RS + fq * 8];
        const bf16x8 a1 = *(const bf16x8*)&Abf[(wrow0 + 16 + fr) * RS + fq * 8];
#pragma unroll
        for (int ct = 0; ct < 8; ++ct) {
            const bf16x8 b = *(const bf16x8*)&Bbf[(ct * 16 + fr) * RS + fq * 8];
            acc[0][ct] = __builtin_amdgcn_mfma_f32_16x16x32_bf16(a0, b, acc[0][ct], 0, 0, 0);
            acc[1][ct] = __builtin_amdgcn_mfma_f32_16x16x32_bf16(a1, b, acc[1][ct], 0, 0, 0);
        }
    }

    // norm partials -> LDS -> per-block global arrays (non-atomic)
#pragma unroll
    for (int q = 0; q < 4; ++q) {
        atomicAdd(&x2s[32 * q + rbase], x2p[q]);
        atomicAdd(&y2s[32 * q + rbase], y2p[q]);
    }
    __syncthreads();
    if (t < BSZ) {
        x2P[bid * BSZ + t] = x2s[t];
        y2P[bid * BSZ + t] = y2s[t];
    }

    // store partial tile: C/D layout col=lane&15, row=quad*4+reg (m89/m91)
    float* Pb = P + ((size_t)bid << 14);
#pragma unroll
    for (int rt = 0; rt < 2; ++rt)
#pragma unroll
        for (int ct = 0; ct < 8; ++ct)
#pragma unroll
            for (int r = 0; r < 4; ++r)
                Pb[(wrow0 + rt * 16 + fq * 4 + r) * BSZ + ct * 16 + fr] = acc[rt][ct][r];
}

// Sum 256 partials (ILP-16), finish norms, build C = sqrt(relu(x2_i + y2_j - 2S)).
__global__ __launch_bounds__(256) void reduce_kernel(
    const float* __restrict__ P, const float* __restrict__ x2P,
    const float* __restrict__ y2P, float* __restrict__ C)
{
    __shared__ float y2loc[BSZ];
    __shared__ float x2loc[2];
    const int t = threadIdx.x;
    const int b = blockIdx.x;          // 64 blocks; rows {2b, 2b+1}
    if (t < 2) x2loc[t] = 0.f;
    __syncthreads();
    if (t < BSZ) {
        float s = 0.f;
#pragma unroll 8
        for (int bb = 0; bb < NBLK1; ++bb) s += y2P[bb * BSZ + t];
        y2loc[t] = s;
    } else {
        const int t2 = t - BSZ;
        const int rsel = t2 >> 6;       // 0/1
        const int part = t2 & 63;       // 64 threads x 4 blocks each
        const int row = 2 * b + rsel;
        float s = 0.f;
#pragma unroll
        for (int m = 0; m < 4; ++m) s += x2P[(part * 4 + m) * BSZ + row];
        atomicAdd(&x2loc[rsel], s);
    }
    __syncthreads();
    const int o = b * 256 + t;
    const int i = o >> 7, j = o & 127;
    float a[16];
#pragma unroll
    for (int m = 0; m < 16; ++m) a[m] = 0.f;
    for (int k0 = 0; k0 < NBLK1; k0 += 16) {
#pragma unroll
        for (int m = 0; m < 16; ++m) a[m] += P[(size_t)(k0 + m) * 16384 + o];
    }
    float s = 0.f;
#pragma unroll
    for (int m = 0; m < 16; ++m) s += a[m];
    C[o] = sqrtf(fmaxf(x2loc[i - 2 * b] + y2loc[j] - 2.f * s, 0.f));
}

// Single-block sinkhorn on prebuilt C; exp-factorized (two 128x128 matvecs/iter).
__global__ __launch_bounds__(1024) void sinkhorn_kernel(
    const float* __restrict__ Cg, float* __restrict__ out)
{
    __shared__ float C_lds[BSZ * BSZ];
    __shared__ float w_s[BSZ];           // exp(-v)
    __shared__ float g_s[BSZ];           // exp(-u)
    __shared__ float u_s[BSZ], v_s[BSZ];
    const int t = threadIdx.x;
    const int lane = t & 63;
    const int wave = t >> 6;
    const int rgrp = wave * 8 + (lane >> 3);
    const int off16 = (lane & 7) * 16;

#pragma unroll
    for (int q = 0; q < 4; ++q)
        *(float4*)&C_lds[q * 4096 + t * 4] = *(const float4*)&Cg[q * 4096 + t * 4];
    if (t < BSZ) w_s[t] = 1.f;
    __syncthreads();

    float rowE[16], colF[16], mrow, mcol;
    {
        float tmp[16]; float m = -1e30f;
#pragma unroll
        for (int k = 0; k < 16; ++k) { tmp[k] = C_lds[rgrp * BSZ + off16 + k]; m = fmaxf(m, tmp[k]); }
        m = fmaxf(m, __shfl_xor(m, 1)); m = fmaxf(m, __shfl_xor(m, 2)); m = fmaxf(m, __shfl_xor(m, 4));
        mrow = m;
#pragma unroll
        for (int k = 0; k < 16; ++k) rowE[k] = __expf(tmp[k] - mrow);
    }
    {
        float tmp[16]; float m = -1e30f;
#pragma unroll
        for (int k = 0; k < 16; ++k) { tmp[k] = C_lds[(off16 + k) * BSZ + rgrp]; m = fmaxf(m, tmp[k]); }
        m = fmaxf(m, __shfl_xor(m, 1)); m = fmaxf(m, __shfl_xor(m, 2)); m = fmaxf(m, __shfl_xor(m, 4));
        mcol = m;
#pragma unroll
        for (int k = 0; k < 16; ++k) colF[k] = __expf(tmp[k] - mcol);
    }

    const float log_ab = -logf(128.f);
    float u_cur = 0.f, v_cur = 0.f;

    for (int it = 0; it < NITER; ++it) {
        float acc = 0.f;
#pragma unroll
        for (int k = 0; k < 16; ++k) acc += rowE[k] * w_s[off16 + k];
        acc += __shfl_xor(acc, 1); acc += __shfl_xor(acc, 2); acc += __shfl_xor(acc, 4);
        const float lse = mrow + __logf(acc);
        u_cur = REGF * (log_ab - lse + u_cur);
        if ((lane & 7) == 0) g_s[rgrp] = __expf(-u_cur);
        __syncthreads();
        float acc2 = 0.f;
#pragma unroll
        for (int k = 0; k < 16; ++k) acc2 += colF[k] * g_s[off16 + k];
        acc2 += __shfl_xor(acc2, 1); acc2 += __shfl_xor(acc2, 2); acc2 += __shfl_xor(acc2, 4);
        const float lse2 = mcol + __logf(acc2);
        v_cur = REGF * (log_ab - lse2 + v_cur);
        if ((lane & 7) == 0) w_s[rgrp] = __expf(-v_cur);
        __syncthreads();
    }

    if ((lane & 7) == 0) { u_s[rgrp] = u_cur; v_s[rgrp] = v_cur; }
    __syncthreads();
    if (t == 0) {
        float su = 0.f;
        for (int i = 0; i < BSZ; ++i) su += u_s[i] + v_s[i];
        out[0] = su / 128.f;
    }
}

extern "C" void kernel_launch(void* const* d_in, const int* in_sizes, int n_in,
                              void* d_out, int out_size, void* d_ws, size_t ws_size,
                              hipStream_t stream) {
    const float* imgs   = (const float*)d_in[0];
    const float* imgs_w = (const float*)d_in[1];
    const float* target = (const float*)d_in[2];
    float* out = (float*)d_out;
    float* wsf = (float*)d_ws;

    float* P   = wsf;                                  // 256 * 16384 partials
    float* x2P = wsf + (size_t)NBLK1 * BSZ * BSZ;      // 256 * 128
    float* y2P = x2P + NBLK1 * BSZ;                    // 256 * 128
    float* C   = y2P + NBLK1 * BSZ;                    // 128 * 128

    dot_kernel<<<NBLK1, 256, 0, stream>>>(imgs, imgs_w, target, P, x2P, y2P);
    reduce_kernel<<<BSZ * BSZ / 256, 256, 0, stream>>>(P, x2P, y2P, C);
    sinkhorn_kernel<<<1, 1024, 0, stream>>>(C, out);
}